// Round 6
// baseline (843.202 us; speedup 1.0000x reference)
//
#include <hip/hip_runtime.h>
#include <cmath>

// Problem constants (fixed by reference): B=8, N=2048, eps=0.01, 50 iters.
#define BATCH 8
#define NPT   2048
#define NPAIR (NPT / 2)               // 1024 column pairs
#define NPTS  (BATCH * NPT)
#define TILES 64                      // blocks per batch (32 rows each)
#define GRID_MAIN (BATCH * TILES)     // 512 blocks = 2/CU (64KB LDS -> both resident)
#define THREADS 512                   // 8 waves/block -> 16 waves/CU = 4/SIMD
#define RPW   4                       // rows per wave
#define ITERS 50

// exp(v_j - 100*cost) = exp2( C_LOG2E*v_j + NEG100C*(n_i + n_j) + S200C*dot )
#define C_LOG2E 1.4426950408889634f
#define NEG100C (-144.26950408889634f)   // -100 * log2(e)
#define S200C   288.53900817779268f      //  200 * log2(e)
#define EPS_LOG 1e-8f
#define LN2_01  0.006931471805599453f    // 0.01 * ln(2)

typedef float v2f __attribute__((ext_vector_type(2)));
typedef float v4f __attribute__((ext_vector_type(4)));
typedef unsigned long long u64t;

static __device__ __forceinline__ float fast_exp2(float x) {
#if __has_builtin(__builtin_amdgcn_exp2f)
    return __builtin_amdgcn_exp2f(x);   // raw v_exp_f32
#else
    return exp2f(x);
#endif
}

// Guaranteed-packed fp32 ops (VOP3P). Pure register asm: non-volatile, no
// memory — compiler can still CSE/reschedule freely.
static __device__ __forceinline__ v2f pk_fma(v2f a, v2f b, v2f c) {
    v2f d;
    asm("v_pk_fma_f32 %0, %1, %2, %3" : "=v"(d) : "v"(a), "v"(b), "v"(c));
    return d;
}
static __device__ __forceinline__ v2f pk_add(v2f a, v2f b) {
    v2f d;
    asm("v_pk_add_f32 %0, %1, %2" : "=v"(d) : "v"(a), "v"(b));
    return d;
}

// Coherence-point (agent-scope, relaxed) accessors for cross-block data.
static __device__ __forceinline__ float gload(const float* p) {
    return __hip_atomic_load(p, __ATOMIC_RELAXED, __HIP_MEMORY_SCOPE_AGENT);
}
static __device__ __forceinline__ void gstore(float* p, float val) {
    __hip_atomic_store(p, val, __ATOMIC_RELAXED, __HIP_MEMORY_SCOPE_AGENT);
}
static __device__ __forceinline__ u64t gload2(const float* p) {   // 2 floats
    return __hip_atomic_load((const u64t*)p, __ATOMIC_RELAXED,
                             __HIP_MEMORY_SCOPE_AGENT);
}

// ---------------------------------------------------------------------------
// Tiny init: zero EMD outputs and per-batch flag arrays.
// ---------------------------------------------------------------------------
__global__ void init_kernel(float* __restrict__ out,
                            unsigned int* __restrict__ flags) {
    int t = threadIdx.x;          // 512 threads
    if (t < BATCH) out[t] = 0.0f;
    flags[t] = 0u;                // BATCH*TILES = 512 flags
}

// ---------------------------------------------------------------------------
// Flag-array barrier: NO atomic RMW, NO acquire ops.
// ---------------------------------------------------------------------------
static __device__ __forceinline__ void flag_barrier(unsigned int* bflags,
                                                    int tile, int wave,
                                                    int lane,
                                                    unsigned int phase) {
    __syncthreads();
    if (wave == 0) {
        if (lane == 0)
            __hip_atomic_store(&bflags[tile], phase, __ATOMIC_RELAXED,
                               __HIP_MEMORY_SCOPE_AGENT);
        while (__hip_atomic_load(&bflags[lane], __ATOMIC_RELAXED,
                                 __HIP_MEMORY_SCOPE_AGENT) < phase) {
            __builtin_amdgcn_s_sleep(1);
        }
    }
    __syncthreads();
    __builtin_amdgcn_sched_barrier(0);   // no code motion across the barrier
}

// ---------------------------------------------------------------------------
// Fold fresh dual values into the w-slots of a ZW tile.
// Thread t owns pairs {2t, 2t+1}  (dual values dual[base+4t .. base+4t+3]),
// fetched as two compiler-tracked 8-byte coherent loads.
// ---------------------------------------------------------------------------
static __device__ __forceinline__ void fold_dual(v4f* cdZW, const float* dual,
        int base, int tid, const float (&Pa)[2], const float (&Pb)[2]) {
    u64t d0 = gload2(dual + base + 4 * tid);
    u64t d1 = gload2(dual + base + 4 * tid + 2);
    float a0 = __uint_as_float((unsigned)d0);
    float b0 = __uint_as_float((unsigned)(d0 >> 32));
    float a1 = __uint_as_float((unsigned)d1);
    float b1 = __uint_as_float((unsigned)(d1 >> 32));
    reinterpret_cast<v2f*>(&cdZW[2 * tid])[1] =
        (v2f){fmaf(C_LOG2E, a0, Pa[0]), fmaf(C_LOG2E, b0, Pb[0])};
    reinterpret_cast<v2f*>(&cdZW[2 * tid + 1])[1] =
        (v2f){fmaf(C_LOG2E, a1, Pa[1]), fmaf(C_LOG2E, b1, Pb[1])};
}

// ---------------------------------------------------------------------------
// One Sinkhorn half-step over pair-packed LDS column tiles:
//   dual_out_i = log_mu - log( sum_j exp2( dot_scl + rc_i + w_j ) + 1e-8 )
// ---------------------------------------------------------------------------
static __device__ __forceinline__ void half_pass(
        const v4f* cdXY, const v4f* cdZW,
        const v2f (&rx)[RPW], const v2f (&ry)[RPW],
        const v2f (&rz)[RPW], const v2f (&rc)[RPW],
        float* __restrict__ dual_out, int outbase, int lane, float log_mu)
{
    v2f acc[RPW];
#pragma unroll
    for (int r = 0; r < RPW; r++) acc[r] = (v2f){0.0f, 0.0f};

#pragma unroll 2
    for (int jp = 0; jp < NPAIR; jp += 64) {
        v4f a  = cdXY[jp + lane];                       // ds_read_b128
        v4f bz = cdZW[jp + lane];                       // ds_read_b128
        v2f xx = __builtin_shufflevector(a,  a,  0, 1);
        v2f yy = __builtin_shufflevector(a,  a,  2, 3);
        v2f zz = __builtin_shufflevector(bz, bz, 0, 1);
        v2f ww = __builtin_shufflevector(bz, bz, 2, 3);
#pragma unroll
        for (int r = 0; r < RPW; r++) {
            v2f t = pk_fma(xx, rx[r], ww);
            t = pk_fma(yy, ry[r], t);
            t = pk_fma(zz, rz[r], t);
            t = pk_add(t, rc[r]);
            acc[r].x += fast_exp2(t.x);   // scalar adds: no re-pack movs
            acc[r].y += fast_exp2(t.y);
        }
    }

    // Reduce: per-row lane sums -> butterfly -> lane r holds row r's total.
    float sel = 1.0f;
#pragma unroll
    for (int r = 0; r < RPW; r++) {
        float s = acc[r].x + acc[r].y;
#pragma unroll
        for (int m = 32; m >= 1; m >>= 1) s += __shfl_xor(s, m, 64);
        if (lane == r) sel = s;
    }
    float res = log_mu - __logf(sel + EPS_LOG);
    if (lane < RPW) gstore(&dual_out[outbase + lane], res);
}

// ---------------------------------------------------------------------------
// Fused persistent kernel: stage both pair-packed column tiles once, run all
// 50 iterations with flag barriers, fused EMD epilogue.
// LDS = 64 KB; 512 blocks x 512 threads -> 2 blocks/CU, 16 waves/CU (4/SIMD).
// ---------------------------------------------------------------------------
__global__ __launch_bounds__(THREADS, 4) void sinkhorn_kernel(
        const float* __restrict__ x1, const float* __restrict__ x2,
        float* __restrict__ u, float* __restrict__ v,
        unsigned int* __restrict__ flags, float* __restrict__ out)
{
    __shared__ v4f cd1XY[NPAIR], cd1ZW[NPAIR];   // side-1 (dual = u)
    __shared__ v4f cd2XY[NPAIR], cd2ZW[NPAIR];   // side-2 (dual = v)

    const int b    = blockIdx.x / TILES;
    const int tile = blockIdx.x % TILES;
    const int base = b * NPT;
    unsigned int* bflags = flags + b * TILES;

    const int tid  = threadIdx.x;
    const int wave = tid >> 6;
    const int lane = tid & 63;
    const int row0 = tile * 32 + wave * RPW;

    const float log_mu = logf(1.0f / (float)NPT + EPS_LOG);   // == log_nu

    // ---- one-time staging: thread t stages pairs {2t, 2t+1} ----
    float P1a[2], P1b[2], P2a[2], P2b[2];
#pragma unroll
    for (int k = 0; k < 2; k++) {
        int q = 2 * tid + k;                     // pair index
        const float* p = x1 + 3 * (base + 2 * q);
        float ax = p[0], ay = p[1], az = p[2];
        float bx = p[3], by = p[4], bz = p[5];
        float na = fmaf(ax, ax, fmaf(ay, ay, az * az));
        float nb = fmaf(bx, bx, fmaf(by, by, bz * bz));
        P1a[k] = na * NEG100C;  P1b[k] = nb * NEG100C;
        cd1XY[q] = (v4f){ax * S200C, bx * S200C, ay * S200C, by * S200C};
        cd1ZW[q] = (v4f){az * S200C, bz * S200C, P1a[k], P1b[k]};

        p = x2 + 3 * (base + 2 * q);
        ax = p[0]; ay = p[1]; az = p[2];
        bx = p[3]; by = p[4]; bz = p[5];
        na = fmaf(ax, ax, fmaf(ay, ay, az * az));
        nb = fmaf(bx, bx, fmaf(by, by, bz * bz));
        P2a[k] = na * NEG100C;  P2b[k] = nb * NEG100C;
        cd2XY[q] = (v4f){ax * S200C, bx * S200C, ay * S200C, by * S200C};
        cd2ZW[q] = (v4f){az * S200C, bz * S200C, P2a[k], P2b[k]};
    }

    // ---- one-time row registers (wave-uniform splats) for both sides ----
    v2f rx1[RPW], ry1[RPW], rz1[RPW], rc1[RPW];
    v2f rx2[RPW], ry2[RPW], rz2[RPW], rc2[RPW];
    float rc1s[RPW];
#pragma unroll
    for (int r = 0; r < RPW; r++) {
        const float* p = x1 + 3 * (base + row0 + r);
        float a = p[0], bb = p[1], c = p[2];
        float nn = NEG100C * fmaf(a, a, fmaf(bb, bb, c * c));
        rx1[r] = (v2f){a, a};  ry1[r] = (v2f){bb, bb};
        rz1[r] = (v2f){c, c};  rc1[r] = (v2f){nn, nn};
        rc1s[r] = nn;
        p = x2 + 3 * (base + row0 + r);
        a = p[0]; bb = p[1]; c = p[2];
        nn = NEG100C * fmaf(a, a, fmaf(bb, bb, c * c));
        rx2[r] = (v2f){a, a};  ry2[r] = (v2f){bb, bb};
        rz2[r] = (v2f){c, c};  rc2[r] = (v2f){nn, nn};
    }
    __syncthreads();

    // ---- 50 Sinkhorn iterations, 2 flag barriers each ----
    unsigned int phase = 0;
    for (int it = 0; it < ITERS; it++) {
        if (it > 0) {   // fold fresh v into cd2 w-slots (iter 0: w=P already)
            fold_dual(cd2ZW, v, base, tid, P2a, P2b);
            __syncthreads();
        }
        // u_i = log_mu - log(sum_j K_ij e^{v_j} + eps)
        half_pass(cd2XY, cd2ZW, rx1, ry1, rz1, rc1, u, base + row0, lane, log_mu);
        flag_barrier(bflags, tile, wave, lane, ++phase);   // publish u

        fold_dual(cd1ZW, u, base, tid, P1a, P1b);          // fold fresh u
        __syncthreads();
        // v_j = log_nu - log(sum_i K_ij e^{u_i} + eps)
        half_pass(cd1XY, cd1ZW, rx2, ry2, rz2, rc2, v, base + row0, lane, log_mu);
        flag_barrier(bflags, tile, wave, lane, ++phase);   // publish v
    }

    // ---- fused EMD epilogue: emd[b] = sum_ij exp2(t) * cost,
    //      cost = 0.01*(u_i+v_j) - 0.01*ln2 * t  (algebraically exact) ----
    v2f* cvp = reinterpret_cast<v2f*>(cd1XY);   // cd1XY space reused (8 KB)
    {
        u64t d0 = gload2(v + base + 4 * tid);
        u64t d1 = gload2(v + base + 4 * tid + 2);
        float a0 = __uint_as_float((unsigned)d0);
        float b0 = __uint_as_float((unsigned)(d0 >> 32));
        float a1 = __uint_as_float((unsigned)d1);
        float b1 = __uint_as_float((unsigned)(d1 >> 32));
        reinterpret_cast<v2f*>(&cd2ZW[2 * tid])[1] =
            (v2f){fmaf(C_LOG2E, a0, P2a[0]), fmaf(C_LOG2E, b0, P2b[0])};
        reinterpret_cast<v2f*>(&cd2ZW[2 * tid + 1])[1] =
            (v2f){fmaf(C_LOG2E, a1, P2a[1]), fmaf(C_LOG2E, b1, P2b[1])};
        cvp[2 * tid]     = (v2f){0.01f * a0, 0.01f * b0};
        cvp[2 * tid + 1] = (v2f){0.01f * a1, 0.01f * b1};
    }
    __syncthreads();

    v2f rcc[RPW], su[RPW];
#pragma unroll
    for (int r = 0; r < RPW; r++) {
        float ur  = gload(&u[base + row0 + r]);
        float rcs = fmaf(C_LOG2E, ur, rc1s[r]);
        rcc[r] = (v2f){rcs, rcs};
        float sus = 0.01f * ur;
        su[r] = (v2f){sus, sus};
    }

    const v2f NL2 = {-LN2_01, -LN2_01};
    v2f eacc = {0.0f, 0.0f};
#pragma unroll 2
    for (int jp = 0; jp < NPAIR; jp += 64) {
        v4f a   = cd2XY[jp + lane];
        v4f bz  = cd2ZW[jp + lane];
        v2f cv2 = cvp[jp + lane];
        v2f xx = __builtin_shufflevector(a,  a,  0, 1);
        v2f yy = __builtin_shufflevector(a,  a,  2, 3);
        v2f zz = __builtin_shufflevector(bz, bz, 0, 1);
        v2f ww = __builtin_shufflevector(bz, bz, 2, 3);
#pragma unroll
        for (int r = 0; r < RPW; r++) {
            v2f t = pk_fma(xx, rx1[r], ww);
            t = pk_fma(yy, ry1[r], t);
            t = pk_fma(zz, rz1[r], t);
            t = pk_add(t, rcc[r]);
            v2f c2 = pk_fma(t, NL2, pk_add(su[r], cv2));
            eacc.x = fmaf(fast_exp2(t.x), c2.x, eacc.x);
            eacc.y = fmaf(fast_exp2(t.y), c2.y, eacc.y);
        }
    }
    float es = eacc.x + eacc.y;
#pragma unroll
    for (int m = 32; m >= 1; m >>= 1) es += __shfl_xor(es, m, 64);

    float* wsum = reinterpret_cast<float*>(cd2XY);   // free space, no reader
    if (lane == 0) wsum[wave] = es;
    __syncthreads();
    if (tid == 0) {
        float s = 0.0f;
#pragma unroll
        for (int w = 0; w < THREADS / 64; w++) s += wsum[w];
        atomicAdd(&out[b], s);
    }
}

// ---------------------------------------------------------------------------
extern "C" void kernel_launch(void* const* d_in, const int* in_sizes, int n_in,
                              void* d_out, int out_size, void* d_ws, size_t ws_size,
                              hipStream_t stream) {
    (void)in_sizes; (void)n_in; (void)out_size; (void)ws_size;
    const float* x1 = (const float*)d_in[0];
    const float* x2 = (const float*)d_in[1];
    float* out = (float*)d_out;

    char* ws = (char*)d_ws;
    float* u = (float*)ws;                             // NPTS floats
    float* v = u + NPTS;                               // NPTS floats
    unsigned int* flags = (unsigned int*)(v + NPTS);   // BATCH*TILES uints

    init_kernel<<<1, 512, 0, stream>>>(out, flags);
    sinkhorn_kernel<<<GRID_MAIN, THREADS, 0, stream>>>(x1, x2, u, v, flags, out);
}